// Round 3
// baseline (2102.776 us; speedup 1.0000x reference)
//
#include <hip/hip_runtime.h>
#include <math.h>

#define H 64
#define W 64
#define HW 4096
#define CH 128
#define CIN 256
#define COUT 384
#define KDIM 1152
#define K3 3456      // 3*KDIM for hi/lo split GEMM
#define NB 4

typedef __bf16 bf16x8 __attribute__((ext_vector_type(8)));
typedef float f32x4 __attribute__((ext_vector_type(4)));

__device__ __forceinline__ void gl_lds16(const __bf16* g, __bf16* l) {
    __builtin_amdgcn_global_load_lds(
        (const __attribute__((address_space(1))) unsigned int*)(g),
        (__attribute__((address_space(3))) unsigned int*)(l), 16, 0, 0);
}

// ---------------- copy former+latter passthrough ----------------
__global__ void copy_passthrough(const float* __restrict__ x, float* __restrict__ out) {
    int idx = blockIdx.x * blockDim.x + threadIdx.x; // over NB*CIN*HW
    if (idx >= NB * CIN * HW) return;
    int b = idx / (CIN * HW);
    int rem = idx - b * (CIN * HW);
    out[(size_t)b * COUT * HW + rem] = x[idx];
}

// ---------------- im2col of former -> A2 = [P_hi | P_lo | P_hi] ----------------
__global__ void build_patches_hilo(const float* __restrict__ former, __bf16* __restrict__ A2) {
    int idx = blockIdx.x * blockDim.x + threadIdx.x; // over HW*KDIM
    if (idx >= HW * KDIM) return;
    int i = idx / KDIM, k = idx - i * KDIM;
    int c = k / 9, q = k - c * 9;
    int dy = q / 3, dx = q - dy * 3;
    int y = (i >> 6) + dy - 1, x = (i & 63) + dx - 1;
    float v = 0.f;
    if ((unsigned)y < H && (unsigned)x < W) v = former[c * HW + y * W + x];
    __bf16 hi = (__bf16)v;
    __bf16 lo = (__bf16)(v - (float)hi);
    size_t base = (size_t)i * K3;
    A2[base + k] = hi;
    A2[base + KDIM + k] = lo;
    A2[base + 2 * KDIM + k] = hi;
}

// ---------------- normalized latter windows -> B2 = [WN_hi | WN_hi | WN_lo], den, mm ----------------
__global__ void build_winn_hilo(const float* __restrict__ latter, const float* __restrict__ mask,
                                const int* __restrict__ mask_thred_p,
                                __bf16* __restrict__ B2, float* __restrict__ den, float* __restrict__ mm) {
    int j = blockIdx.x;               // patch index
    int y0 = j >> 6, x0 = j & 63;
    __shared__ float red[256];
    float vals[5];
    float ss = 0.f;
    for (int t = 0; t < 5; ++t) {
        int k = threadIdx.x + t * 256;
        float v = 0.f;
        if (k < KDIM) {
            int c = k / 9, q = k - c * 9;
            int dy = q / 3, dx = q - dy * 3;
            int y = y0 + dy - 1, x = x0 + dx - 1;
            if ((unsigned)y < H && (unsigned)x < W) v = latter[c * HW + y * W + x];
        }
        vals[t] = v;
        ss += v * v;
    }
    red[threadIdx.x] = ss;
    __syncthreads();
    for (int s = 128; s > 0; s >>= 1) {
        if (threadIdx.x < s) red[threadIdx.x] += red[threadIdx.x + s];
        __syncthreads();
    }
    float d = fmaxf(sqrtf(red[0]), 1e-4f);
    float inv = 1.f / d;
    size_t base = (size_t)j * K3;
    for (int t = 0; t < 5; ++t) {
        int k = threadIdx.x + t * 256;
        if (k < KDIM) {
            float v = vals[t] * inv;
            __bf16 hi = (__bf16)v;
            __bf16 lo = (__bf16)(v - (float)hi);
            B2[base + k] = hi;
            B2[base + KDIM + k] = hi;
            B2[base + 2 * KDIM + k] = lo;
        }
    }
    if (threadIdx.x == 0) {
        den[j] = d;
        float s = 0.f;
        for (int q = 0; q < 9; ++q) {
            int dy = q / 3, dx = q - dy * 3;
            int y = y0 + dy - 1, x = x0 + dx - 1;
            if ((unsigned)y < H && (unsigned)x < W) s += mask[y * W + x];
        }
        float mmean = s / 9.f;
        float thr = (float)mask_thred_p[0] / 9.f;
        mm[j] = (mmean <= thr) ? 1.f : 0.f;
    }
}

// ---------------- MFMA bf16 NT GEMM with XOR-swizzled LDS ----------------
// C[M,N] = A[M,K] * B[N,K]^T, fp32 out. 128x128 tile, BK=32.
// LDS physical slot s (16B each): row=s>>2, phys_kseg=s&3 holds logical
// kseg = (s&3) ^ ((row>>1)&3). Frag read of logical kseg=quad at row r is at
// phys (quad ^ ((r>>1)&3)) -> 16 lanes spread over 8 bank-quads, 2-way (free).
__launch_bounds__(256)
__global__ void gemm_bf16_nt(const __bf16* __restrict__ A, const __bf16* __restrict__ B,
                             float* __restrict__ C, int K, int ldc) {
    __shared__ __bf16 As[128 * 32];
    __shared__ __bf16 Bs[128 * 32];
    int tid = threadIdx.x;
    int wave = tid >> 6, lane = tid & 63;
    int quad = lane >> 4, lr = lane & 15;
    int wr = wave >> 1, wc = wave & 1;
    int i0 = blockIdx.y * 128, j0 = blockIdx.x * 128;

    // staging slots: s0 = tid, s1 = tid + 256; both have same logical kseg perm
    int r0 = tid >> 2;            // 0..63
    int r1 = r0 + 64;             // 64..127
    int lk = ((tid & 3) ^ ((tid >> 3) & 3)) * 8;   // logical k offset (elements)

    f32x4 acc[4][4];
    #pragma unroll
    for (int a = 0; a < 4; ++a)
        #pragma unroll
        for (int b = 0; b < 4; ++b) acc[a][b] = (f32x4){0.f, 0.f, 0.f, 0.f};

    const __bf16* Ab = A + (size_t)i0 * K;
    const __bf16* Bb = B + (size_t)j0 * K;
    size_t off0 = (size_t)r0 * K + lk;
    size_t off1 = (size_t)r1 * K + lk;

    // frag read addresses (elements)
    int ra_addr[4], rb_addr[4];
    #pragma unroll
    for (int t = 0; t < 4; ++t) {
        int rowA = wr * 64 + t * 16 + lr;
        ra_addr[t] = rowA * 32 + ((quad ^ ((rowA >> 1) & 3)) * 8);
        int rowB = wc * 64 + t * 16 + lr;
        rb_addr[t] = rowB * 32 + ((quad ^ ((rowB >> 1) & 3)) * 8);
    }

    for (int k0 = 0; k0 < K; k0 += 32) {
        __syncthreads();
        gl_lds16(Ab + off0 + k0, As + tid * 8);
        gl_lds16(Ab + off1 + k0, As + (tid + 256) * 8);
        gl_lds16(Bb + off0 + k0, Bs + tid * 8);
        gl_lds16(Bb + off1 + k0, Bs + (tid + 256) * 8);
        __syncthreads();
        bf16x8 af[4], bfr[4];
        #pragma unroll
        for (int mi = 0; mi < 4; ++mi) af[mi] = *(const bf16x8*)(As + ra_addr[mi]);
        #pragma unroll
        for (int ni = 0; ni < 4; ++ni) bfr[ni] = *(const bf16x8*)(Bs + rb_addr[ni]);
        #pragma unroll
        for (int mi = 0; mi < 4; ++mi)
            #pragma unroll
            for (int ni = 0; ni < 4; ++ni)
                acc[mi][ni] = __builtin_amdgcn_mfma_f32_16x16x32_bf16(af[mi], bfr[ni], acc[mi][ni], 0, 0, 0);
    }

    #pragma unroll
    for (int mi = 0; mi < 4; ++mi) {
        #pragma unroll
        for (int r = 0; r < 4; ++r) {
            int row = i0 + wr * 64 + mi * 16 + quad * 4 + r;
            float* Cr = C + (size_t)row * ldc + j0 + wc * 64 + lr;
            #pragma unroll
            for (int ni = 0; ni < 4; ++ni)
                Cr[ni * 16] = acc[mi][ni][r];
        }
    }
}

// ---------------- pass A: E1[g,h] = diagbox3(S)[p, rm(h)], g = rm(p) ----------------
// Blocks ordered by p so consecutive blocks read consecutive S rows (L2-hot).
__launch_bounds__(256)
__global__ void diag_perm(const float* __restrict__ S, float* __restrict__ E1) {
    int p = blockIdx.x;
    int g = ((p & 63) << 6) | (p >> 6);   // rm(p)
    __shared__ float lds[3][64 * 65];
    for (int rr = 0; rr < 3; ++rr) {
        int pr = p + rr - 1;
        bool v = (unsigned)pr < HW;
        const float* Sr = S + (size_t)pr * HW;
        for (int idx = threadIdx.x; idx < HW; idx += 256) {
            float val = v ? Sr[idx] : 0.f;
            lds[rr][(idx & 63) * 65 + (idx >> 6)] = val;  // transpose-swizzled store
        }
    }
    __syncthreads();
    for (int h = threadIdx.x; h < HW; h += 256) {
        int q = ((h & 63) << 6) | (h >> 6);  // rm(h)
        float s = 0.f;
        #pragma unroll
        for (int d1 = -1; d1 <= 1; ++d1) {
            int pp = p + d1, qq = q + d1;
            if ((unsigned)pp < HW && (unsigned)qq < HW)
                s += lds[d1 + 1][(qq & 63) * 65 + (qq >> 6)];
        }
        E1[(size_t)g * HW + h] = s;
    }
}

// ---------------- pass B: D2 = diagbox3(E1); softmax over h; *mm*den; bf16 out ----------------
__launch_bounds__(256)
__global__ void diag_softmax(const float* __restrict__ E1, const float* __restrict__ mm,
                             const float* __restrict__ den, __bf16* __restrict__ YB) {
    int g = blockIdx.x;
    __shared__ float red[256];
    float lv[16], sv[16];
    float lmax = -1e30f;
    #pragma unroll
    for (int t = 0; t < 16; ++t) {
        int h = threadIdx.x + t * 256;
        float s = 0.f;
        #pragma unroll
        for (int d2 = -1; d2 <= 1; ++d2) {
            int gg = g + d2, hh = h + d2;
            if ((unsigned)gg < HW && (unsigned)hh < HW)
                s += E1[(size_t)gg * HW + hh];
        }
        int j = ((h & 63) << 6) | (h >> 6);  // rm(h)
        float m = mm[j];
        float l = 10.f * s * m;
        lv[t] = l;
        sv[t] = m * den[j];
        lmax = fmaxf(lmax, l);
    }
    red[threadIdx.x] = lmax;
    __syncthreads();
    for (int s = 128; s > 0; s >>= 1) {
        if (threadIdx.x < s) red[threadIdx.x] = fmaxf(red[threadIdx.x], red[threadIdx.x + s]);
        __syncthreads();
    }
    float M = red[0];
    __syncthreads();
    float ev[16];
    float ssum = 0.f;
    #pragma unroll
    for (int t = 0; t < 16; ++t) {
        ev[t] = expf(lv[t] - M);
        ssum += ev[t];
    }
    red[threadIdx.x] = ssum;
    __syncthreads();
    for (int s = 128; s > 0; s >>= 1) {
        if (threadIdx.x < s) red[threadIdx.x] += red[threadIdx.x + s];
        __syncthreads();
    }
    float inv = 1.f / red[0];
    #pragma unroll
    for (int t = 0; t < 16; ++t) {
        int h = threadIdx.x + t * 256;
        YB[(size_t)g * HW + h] = (__bf16)(ev[t] * inv * sv[t]);
    }
}

// ---------------- WNT[n, h] = WN_hi[rm(h)][n]  (bf16, K-contiguous for GEMM2) ----------------
__launch_bounds__(256)
__global__ void wnt_transpose(const __bf16* __restrict__ B2, __bf16* __restrict__ WNT) {
    int bx = blockIdx.x;  // h-tile (64 wide): h = bx*64 + l -> j = l*64 + bx
    int by = blockIdx.y;  // n-tile
    int n0 = by * 64;
    __shared__ unsigned short tile[64][72];  // pitch 72 ushorts = 144B (16B aligned)
    for (int c = threadIdx.x; c < 512; c += 256) {
        int l = c >> 3, seg = c & 7;
        int j = l * 64 + bx;
        uint4 v = *(const uint4*)(B2 + (size_t)j * K3 + n0 + seg * 8);
        *(uint4*)&tile[l][seg * 8] = v;
    }
    __syncthreads();
    for (int c = threadIdx.x; c < 512; c += 256) {
        int r = c >> 3, seg = c & 7;
        unsigned short tmp[8];
        #pragma unroll
        for (int u = 0; u < 8; ++u) tmp[u] = tile[seg * 8 + u][r];
        *(uint4*)(WNT + (size_t)(n0 + r) * HW + bx * 64 + seg * 8) = *(uint4*)tmp;
    }
}

// ---------------- fold C2T (KDIM x HW, cols g = x*64+y) into shift output ----------------
__launch_bounds__(256)
__global__ void fold_out_t(const float* __restrict__ C2T, float* __restrict__ outb) {
    int c = blockIdx.x;
    __shared__ float lds[64 * 65];
    const float* base = C2T + (size_t)c * 9 * HW;
    #pragma unroll 4
    for (int t = 0; t < 16; ++t) {
        int pos = threadIdx.x + t * 256;   // pos = x*64 + y (column-major pixel)
        int x = pos >> 6, y = pos & 63;
        float s = 0.f;
        #pragma unroll
        for (int dy = 0; dy < 3; ++dy) {
            int yy = y + 1 - dy;
            if ((unsigned)yy >= 64) continue;
            #pragma unroll
            for (int dx = 0; dx < 3; ++dx) {
                int xx = x + 1 - dx;
                if ((unsigned)xx >= 64) continue;
                s += base[(size_t)(dy * 3 + dx) * HW + xx * 64 + yy];
            }
        }
        lds[y * 65 + x] = s * (1.f / 9.f);
    }
    __syncthreads();
    #pragma unroll 4
    for (int t = 0; t < 16; ++t) {
        int pix = threadIdx.x + t * 256;   // pix = y*64 + x (row-major)
        outb[(size_t)(CIN + c) * HW + pix] = lds[(pix >> 6) * 65 + (pix & 63)];
    }
}

extern "C" void kernel_launch(void* const* d_in, const int* in_sizes, int n_in,
                              void* d_out, int out_size, void* d_ws, size_t ws_size,
                              hipStream_t stream) {
    const float* x = (const float*)d_in[0];
    const float* mask = (const float*)d_in[1];
    const int* mask_thred = (const int*)d_in[3];
    float* out = (float*)d_out;

    char* ws = (char*)d_ws;
    __bf16* A2 = (__bf16*)(ws);                         // 28,311,552 B
    __bf16* B2 = (__bf16*)(ws + 28311552);              // 28,311,552 B
    float*  S  = (float*)(ws + 56623104);               // 67,108,864 B
    float*  E1 = (float*)(ws + 123731968);              // 67,108,864 B
    float* den = (float*)(ws + 190840832);              // 16,384 B
    float* mmb = (float*)(ws + 190857216);              // 16,384 B
    // aliases (lifetimes disjoint): YB over S; WNT + C2T over E1
    __bf16* YB  = (__bf16*)S;                           // 32 MB
    __bf16* WNT = (__bf16*)E1;                          // 9.4 MB
    float*  C2T = (float*)(ws + 123731968 + 9437184);   // 18.9 MB (1152 x 4096 fp32)

    copy_passthrough<<<(NB * CIN * HW + 255) / 256, 256, 0, stream>>>(x, out);

    for (int b = 0; b < NB; ++b) {
        const float* xb = x + (size_t)b * CIN * HW;
        const float* former = xb;
        const float* latter = xb + (size_t)CH * HW;
        const float* maskb = mask + (size_t)b * HW;
        float* outb = out + (size_t)b * COUT * HW;

        build_patches_hilo<<<(HW * KDIM + 255) / 256, 256, 0, stream>>>(former, A2);
        build_winn_hilo<<<HW, 256, 0, stream>>>(latter, maskb, mask_thred, B2, den, mmb);
        gemm_bf16_nt<<<dim3(32, 32), 256, 0, stream>>>(A2, B2, S, K3, HW);
        diag_perm<<<HW, 256, 0, stream>>>(S, E1);
        diag_softmax<<<HW, 256, 0, stream>>>(E1, mmb, den, YB);
        wnt_transpose<<<dim3(64, KDIM / 64), 256, 0, stream>>>(B2, WNT);
        // C2T[n][g] = sum_h WNT[n][h] * YB[g][h]  (M=1152, N=4096, K=4096)
        gemm_bf16_nt<<<dim3(32, KDIM / 128), 256, 0, stream>>>(WNT, YB, C2T, HW, HW);
        fold_out_t<<<CH, 256, 0, stream>>>(C2T, outb);
    }
}

// Round 4
// 1871.706 us; speedup vs baseline: 1.1235x; 1.1235x over previous
//
#include <hip/hip_runtime.h>
#include <math.h>

#define H 64
#define W 64
#define HW 4096
#define CH 128
#define CIN 256
#define COUT 384
#define KDIM 1152
#define K3 3456      // 3*KDIM for hi/lo split GEMM
#define NB 4

typedef __bf16 bf16x8 __attribute__((ext_vector_type(8)));
typedef float f32x4 __attribute__((ext_vector_type(4)));

__device__ __forceinline__ void gl_lds16(const __bf16* g, __bf16* l) {
    __builtin_amdgcn_global_load_lds(
        (const __attribute__((address_space(1))) unsigned int*)(g),
        (__attribute__((address_space(3))) unsigned int*)(l), 16, 0, 0);
}

// ---------------- copy former+latter passthrough ----------------
__global__ void copy_passthrough(const float* __restrict__ x, float* __restrict__ out) {
    int idx = blockIdx.x * blockDim.x + threadIdx.x; // over NB*CIN*HW
    if (idx >= NB * CIN * HW) return;
    int b = idx / (CIN * HW);
    int rem = idx - b * (CIN * HW);
    out[(size_t)b * COUT * HW + rem] = x[idx];
}

// ---------------- im2col of former -> A2 = [P_hi | P_lo | P_hi] ----------------
__global__ void build_patches_hilo(const float* __restrict__ former, __bf16* __restrict__ A2) {
    int idx = blockIdx.x * blockDim.x + threadIdx.x; // over HW*KDIM
    if (idx >= HW * KDIM) return;
    int i = idx / KDIM, k = idx - i * KDIM;
    int c = k / 9, q = k - c * 9;
    int dy = q / 3, dx = q - dy * 3;
    int y = (i >> 6) + dy - 1, x = (i & 63) + dx - 1;
    float v = 0.f;
    if ((unsigned)y < H && (unsigned)x < W) v = former[c * HW + y * W + x];
    __bf16 hi = (__bf16)v;
    __bf16 lo = (__bf16)(v - (float)hi);
    size_t base = (size_t)i * K3;
    A2[base + k] = hi;
    A2[base + KDIM + k] = lo;
    A2[base + 2 * KDIM + k] = hi;
}

// ---------------- normalized latter windows -> B2 = [WN_hi | WN_hi | WN_lo], den, mm ----------------
__global__ void build_winn_hilo(const float* __restrict__ latter, const float* __restrict__ mask,
                                const int* __restrict__ mask_thred_p,
                                __bf16* __restrict__ B2, float* __restrict__ den, float* __restrict__ mm) {
    int j = blockIdx.x;               // patch index
    int y0 = j >> 6, x0 = j & 63;
    __shared__ float red[256];
    float vals[5];
    float ss = 0.f;
    for (int t = 0; t < 5; ++t) {
        int k = threadIdx.x + t * 256;
        float v = 0.f;
        if (k < KDIM) {
            int c = k / 9, q = k - c * 9;
            int dy = q / 3, dx = q - dy * 3;
            int y = y0 + dy - 1, x = x0 + dx - 1;
            if ((unsigned)y < H && (unsigned)x < W) v = latter[c * HW + y * W + x];
        }
        vals[t] = v;
        ss += v * v;
    }
    red[threadIdx.x] = ss;
    __syncthreads();
    for (int s = 128; s > 0; s >>= 1) {
        if (threadIdx.x < s) red[threadIdx.x] += red[threadIdx.x + s];
        __syncthreads();
    }
    float d = fmaxf(sqrtf(red[0]), 1e-4f);
    float inv = 1.f / d;
    size_t base = (size_t)j * K3;
    for (int t = 0; t < 5; ++t) {
        int k = threadIdx.x + t * 256;
        if (k < KDIM) {
            float v = vals[t] * inv;
            __bf16 hi = (__bf16)v;
            __bf16 lo = (__bf16)(v - (float)hi);
            B2[base + k] = hi;
            B2[base + KDIM + k] = hi;
            B2[base + 2 * KDIM + k] = lo;
        }
    }
    if (threadIdx.x == 0) {
        den[j] = d;
        float s = 0.f;
        for (int q = 0; q < 9; ++q) {
            int dy = q / 3, dx = q - dy * 3;
            int y = y0 + dy - 1, x = x0 + dx - 1;
            if ((unsigned)y < H && (unsigned)x < W) s += mask[y * W + x];
        }
        float mmean = s / 9.f;
        float thr = (float)mask_thred_p[0] / 9.f;
        mm[j] = (mmean <= thr) ? 1.f : 0.f;
    }
}

// ---------------- GEMM1: MFMA bf16 NT, 128x128 tile, BK=64, XOR-swizzled LDS ----------------
// C[M,N] = A[M,K] * B[N,K]^T. LDS row = 64 elem = 128B = all 32 banks, so
// logical kseg (8 per row) is stored at phys = kseg ^ (row&7).
__launch_bounds__(256)
__global__ void gemm_bf16_nt(const __bf16* __restrict__ A, const __bf16* __restrict__ B,
                             float* __restrict__ C, int K, int ldc) {
    __shared__ __bf16 As[128 * 64];
    __shared__ __bf16 Bs[128 * 64];
    int tid = threadIdx.x;
    int wave = tid >> 6, lane = tid & 63;
    int quad = lane >> 4, lr = lane & 15;
    int wr = wave >> 1, wc = wave & 1;
    int i0 = blockIdx.y * 128, j0 = blockIdx.x * 128;

    // staging: slot s = tid + j*256 (j=0..3); row = s>>3, seg = s&7
    int r0 = tid >> 3;                       // 0..31
    int lk = ((tid & 7) ^ ((tid >> 3) & 7)) * 8;  // logical k offset (elements), same for all j

    f32x4 acc[4][4];
    #pragma unroll
    for (int a = 0; a < 4; ++a)
        #pragma unroll
        for (int b = 0; b < 4; ++b) acc[a][b] = (f32x4){0.f, 0.f, 0.f, 0.f};

    const __bf16* Ab = A + (size_t)i0 * K;
    const __bf16* Bb = B + (size_t)j0 * K;

    // frag read addresses (elements): row*64 + (quad+4*s ^ (row&7))*8; row&7 == lr&7
    int ra[4][2], rb[4][2];
    #pragma unroll
    for (int t = 0; t < 4; ++t) {
        int rowA = wr * 64 + t * 16 + lr;
        int rowB = wc * 64 + t * 16 + lr;
        #pragma unroll
        for (int s = 0; s < 2; ++s) {
            ra[t][s] = rowA * 64 + (((quad + 4 * s) ^ (lr & 7)) * 8);
            rb[t][s] = rowB * 64 + (((quad + 4 * s) ^ (lr & 7)) * 8);
        }
    }

    for (int k0 = 0; k0 < K; k0 += 64) {
        __syncthreads();
        #pragma unroll
        for (int j = 0; j < 4; ++j) {
            int row = r0 + j * 32;
            gl_lds16(Ab + (size_t)row * K + k0 + lk, As + (tid + j * 256) * 8);
            gl_lds16(Bb + (size_t)row * K + k0 + lk, Bs + (tid + j * 256) * 8);
        }
        __syncthreads();
        #pragma unroll
        for (int s = 0; s < 2; ++s) {
            bf16x8 af[4], bfr[4];
            #pragma unroll
            for (int mi = 0; mi < 4; ++mi) af[mi] = *(const bf16x8*)(As + ra[mi][s]);
            #pragma unroll
            for (int ni = 0; ni < 4; ++ni) bfr[ni] = *(const bf16x8*)(Bs + rb[ni][s]);
            #pragma unroll
            for (int mi = 0; mi < 4; ++mi)
                #pragma unroll
                for (int ni = 0; ni < 4; ++ni)
                    acc[mi][ni] = __builtin_amdgcn_mfma_f32_16x16x32_bf16(af[mi], bfr[ni], acc[mi][ni], 0, 0, 0);
        }
    }

    #pragma unroll
    for (int mi = 0; mi < 4; ++mi) {
        #pragma unroll
        for (int r = 0; r < 4; ++r) {
            int row = i0 + wr * 64 + mi * 16 + quad * 4 + r;
            float* Cr = C + (size_t)row * ldc + j0 + wc * 64 + lr;
            #pragma unroll
            for (int ni = 0; ni < 4; ++ni)
                Cr[ni * 16] = acc[mi][ni][r];
        }
    }
}

// ---------------- GEMM2: MFMA bf16 NT, 128(M)x64(N) tile, BK=64 ----------------
// Small-M GEMM: grid (N/64, M/128) = (64, 9) = 576 blocks for occupancy.
__launch_bounds__(256)
__global__ void gemm2_bf16_nt(const __bf16* __restrict__ A, const __bf16* __restrict__ B,
                              float* __restrict__ C, int K, int ldc) {
    __shared__ __bf16 As[128 * 64];
    __shared__ __bf16 Bs[64 * 64];
    int tid = threadIdx.x;
    int wave = tid >> 6, lane = tid & 63;
    int quad = lane >> 4, lr = lane & 15;
    int wr = wave >> 1, wc = wave & 1;
    int i0 = blockIdx.y * 128, j0 = blockIdx.x * 64;

    int r0 = tid >> 3;                       // 0..31
    int lk = ((tid & 7) ^ ((tid >> 3) & 7)) * 8;

    f32x4 acc[4][2];
    #pragma unroll
    for (int a = 0; a < 4; ++a)
        #pragma unroll
        for (int b = 0; b < 2; ++b) acc[a][b] = (f32x4){0.f, 0.f, 0.f, 0.f};

    const __bf16* Ab = A + (size_t)i0 * K;
    const __bf16* Bb = B + (size_t)j0 * K;

    int ra[4][2], rb[2][2];
    #pragma unroll
    for (int t = 0; t < 4; ++t) {
        int rowA = wr * 64 + t * 16 + lr;
        #pragma unroll
        for (int s = 0; s < 2; ++s)
            ra[t][s] = rowA * 64 + (((quad + 4 * s) ^ (lr & 7)) * 8);
    }
    #pragma unroll
    for (int t = 0; t < 2; ++t) {
        int rowB = wc * 32 + t * 16 + lr;
        #pragma unroll
        for (int s = 0; s < 2; ++s)
            rb[t][s] = rowB * 64 + (((quad + 4 * s) ^ (lr & 7)) * 8);
    }

    for (int k0 = 0; k0 < K; k0 += 64) {
        __syncthreads();
        #pragma unroll
        for (int j = 0; j < 4; ++j) {
            int row = r0 + j * 32;
            gl_lds16(Ab + (size_t)row * K + k0 + lk, As + (tid + j * 256) * 8);
        }
        #pragma unroll
        for (int j = 0; j < 2; ++j) {
            int row = r0 + j * 32;
            gl_lds16(Bb + (size_t)row * K + k0 + lk, Bs + (tid + j * 256) * 8);
        }
        __syncthreads();
        #pragma unroll
        for (int s = 0; s < 2; ++s) {
            bf16x8 af[4], bfr[2];
            #pragma unroll
            for (int mi = 0; mi < 4; ++mi) af[mi] = *(const bf16x8*)(As + ra[mi][s]);
            #pragma unroll
            for (int ni = 0; ni < 2; ++ni) bfr[ni] = *(const bf16x8*)(Bs + rb[ni][s]);
            #pragma unroll
            for (int mi = 0; mi < 4; ++mi)
                #pragma unroll
                for (int ni = 0; ni < 2; ++ni)
                    acc[mi][ni] = __builtin_amdgcn_mfma_f32_16x16x32_bf16(af[mi], bfr[ni], acc[mi][ni], 0, 0, 0);
        }
    }

    #pragma unroll
    for (int mi = 0; mi < 4; ++mi) {
        #pragma unroll
        for (int r = 0; r < 4; ++r) {
            int row = i0 + wr * 64 + mi * 16 + quad * 4 + r;
            float* Cr = C + (size_t)row * ldc + j0 + wc * 32 + lr;
            #pragma unroll
            for (int ni = 0; ni < 2; ++ni)
                Cr[ni * 16] = acc[mi][ni][r];
        }
    }
}

// ---------------- pass A: E1[g,h] = diagbox3(S)[p, rm(h)], g = rm(p) ----------------
__launch_bounds__(256)
__global__ void diag_perm(const float* __restrict__ S, float* __restrict__ E1) {
    int p = blockIdx.x;
    int g = ((p & 63) << 6) | (p >> 6);   // rm(p)
    __shared__ float lds[3][64 * 65];
    for (int rr = 0; rr < 3; ++rr) {
        int pr = p + rr - 1;
        bool v = (unsigned)pr < HW;
        const float* Sr = S + (size_t)pr * HW;
        for (int idx = threadIdx.x; idx < HW; idx += 256) {
            float val = v ? Sr[idx] : 0.f;
            lds[rr][(idx & 63) * 65 + (idx >> 6)] = val;  // transpose-swizzled store
        }
    }
    __syncthreads();
    for (int h = threadIdx.x; h < HW; h += 256) {
        int q = ((h & 63) << 6) | (h >> 6);  // rm(h)
        float s = 0.f;
        #pragma unroll
        for (int d1 = -1; d1 <= 1; ++d1) {
            int pp = p + d1, qq = q + d1;
            if ((unsigned)pp < HW && (unsigned)qq < HW)
                s += lds[d1 + 1][(qq & 63) * 65 + (qq >> 6)];
        }
        E1[(size_t)g * HW + h] = s;
    }
}

// ---------------- pass B: D2 = diagbox3(E1); softmax over h; *mm*den; bf16 out ----------------
__launch_bounds__(256)
__global__ void diag_softmax(const float* __restrict__ E1, const float* __restrict__ mm,
                             const float* __restrict__ den, __bf16* __restrict__ YB) {
    int g = blockIdx.x;
    __shared__ float red[256];
    float lv[16], sv[16];
    float lmax = -1e30f;
    #pragma unroll
    for (int t = 0; t < 16; ++t) {
        int h = threadIdx.x + t * 256;
        float s = 0.f;
        #pragma unroll
        for (int d2 = -1; d2 <= 1; ++d2) {
            int gg = g + d2, hh = h + d2;
            if ((unsigned)gg < HW && (unsigned)hh < HW)
                s += E1[(size_t)gg * HW + hh];
        }
        int j = ((h & 63) << 6) | (h >> 6);  // rm(h)
        float m = mm[j];
        float l = 10.f * s * m;
        lv[t] = l;
        sv[t] = m * den[j];
        lmax = fmaxf(lmax, l);
    }
    red[threadIdx.x] = lmax;
    __syncthreads();
    for (int s = 128; s > 0; s >>= 1) {
        if (threadIdx.x < s) red[threadIdx.x] = fmaxf(red[threadIdx.x], red[threadIdx.x + s]);
        __syncthreads();
    }
    float M = red[0];
    __syncthreads();
    float ev[16];
    float ssum = 0.f;
    #pragma unroll
    for (int t = 0; t < 16; ++t) {
        ev[t] = expf(lv[t] - M);
        ssum += ev[t];
    }
    red[threadIdx.x] = ssum;
    __syncthreads();
    for (int s = 128; s > 0; s >>= 1) {
        if (threadIdx.x < s) red[threadIdx.x] += red[threadIdx.x + s];
        __syncthreads();
    }
    float inv = 1.f / red[0];
    #pragma unroll
    for (int t = 0; t < 16; ++t) {
        int h = threadIdx.x + t * 256;
        YB[(size_t)g * HW + h] = (__bf16)(ev[t] * inv * sv[t]);
    }
}

// ---------------- WNT[n, h] = WN_hi[rm(h)][n]  (bf16, K-contiguous for GEMM2) ----------------
__launch_bounds__(256)
__global__ void wnt_transpose(const __bf16* __restrict__ B2, __bf16* __restrict__ WNT) {
    int bx = blockIdx.x;  // h-tile (64 wide): h = bx*64 + l -> j = l*64 + bx
    int by = blockIdx.y;  // n-tile
    int n0 = by * 64;
    __shared__ unsigned short tile[64][72];
    for (int c = threadIdx.x; c < 512; c += 256) {
        int l = c >> 3, seg = c & 7;
        int j = l * 64 + bx;
        uint4 v = *(const uint4*)(B2 + (size_t)j * K3 + n0 + seg * 8);
        *(uint4*)&tile[l][seg * 8] = v;
    }
    __syncthreads();
    for (int c = threadIdx.x; c < 512; c += 256) {
        int r = c >> 3, seg = c & 7;
        unsigned short tmp[8];
        #pragma unroll
        for (int u = 0; u < 8; ++u) tmp[u] = tile[seg * 8 + u][r];
        *(uint4*)(WNT + (size_t)(n0 + r) * HW + bx * 64 + seg * 8) = *(uint4*)tmp;
    }
}

// ---------------- fold C2T (KDIM x HW, cols g = x*64+y) into shift output ----------------
__launch_bounds__(256)
__global__ void fold_out_t(const float* __restrict__ C2T, float* __restrict__ outb) {
    int c = blockIdx.x;
    __shared__ float lds[64 * 65];
    const float* base = C2T + (size_t)c * 9 * HW;
    #pragma unroll 4
    for (int t = 0; t < 16; ++t) {
        int pos = threadIdx.x + t * 256;   // pos = x*64 + y (column-major pixel)
        int x = pos >> 6, y = pos & 63;
        float s = 0.f;
        #pragma unroll
        for (int dy = 0; dy < 3; ++dy) {
            int yy = y + 1 - dy;
            if ((unsigned)yy >= 64) continue;
            #pragma unroll
            for (int dx = 0; dx < 3; ++dx) {
                int xx = x + 1 - dx;
                if ((unsigned)xx >= 64) continue;
                s += base[(size_t)(dy * 3 + dx) * HW + xx * 64 + yy];
            }
        }
        lds[y * 65 + x] = s * (1.f / 9.f);
    }
    __syncthreads();
    #pragma unroll 4
    for (int t = 0; t < 16; ++t) {
        int pix = threadIdx.x + t * 256;   // pix = y*64 + x (row-major)
        outb[(size_t)(CIN + c) * HW + pix] = lds[(pix >> 6) * 65 + (pix & 63)];
    }
}

extern "C" void kernel_launch(void* const* d_in, const int* in_sizes, int n_in,
                              void* d_out, int out_size, void* d_ws, size_t ws_size,
                              hipStream_t stream) {
    const float* x = (const float*)d_in[0];
    const float* mask = (const float*)d_in[1];
    const int* mask_thred = (const int*)d_in[3];
    float* out = (float*)d_out;

    char* ws = (char*)d_ws;
    __bf16* A2 = (__bf16*)(ws);
    __bf16* B2 = (__bf16*)(ws + 28311552);
    float*  S  = (float*)(ws + 56623104);
    float*  E1 = (float*)(ws + 123731968);
    float* den = (float*)(ws + 190840832);
    float* mmb = (float*)(ws + 190857216);
    __bf16* YB  = (__bf16*)S;
    __bf16* WNT = (__bf16*)E1;
    float*  C2T = (float*)(ws + 123731968 + 9437184);

    copy_passthrough<<<(NB * CIN * HW + 255) / 256, 256, 0, stream>>>(x, out);

    for (int b = 0; b < NB; ++b) {
        const float* xb = x + (size_t)b * CIN * HW;
        const float* former = xb;
        const float* latter = xb + (size_t)CH * HW;
        const float* maskb = mask + (size_t)b * HW;
        float* outb = out + (size_t)b * COUT * HW;

        build_patches_hilo<<<(HW * KDIM + 255) / 256, 256, 0, stream>>>(former, A2);
        build_winn_hilo<<<HW, 256, 0, stream>>>(latter, maskb, mask_thred, B2, den, mmb);
        gemm_bf16_nt<<<dim3(32, 32), 256, 0, stream>>>(A2, B2, S, K3, HW);
        diag_perm<<<HW, 256, 0, stream>>>(S, E1);
        diag_softmax<<<HW, 256, 0, stream>>>(E1, mmb, den, YB);
        wnt_transpose<<<dim3(64, KDIM / 64), 256, 0, stream>>>(B2, WNT);
        // C2T[n][g] = sum_h WNT[n][h] * YB[g][h]  (M=1152, N=4096, K=4096)
        gemm2_bf16_nt<<<dim3(64, KDIM / 128), 256, 0, stream>>>(WNT, YB, C2T, HW, HW);
        fold_out_t<<<CH, 256, 0, stream>>>(C2T, outb);
    }
}

// Round 5
// 1813.713 us; speedup vs baseline: 1.1594x; 1.0320x over previous
//
#include <hip/hip_runtime.h>
#include <math.h>

#define H 64
#define W 64
#define HW 4096
#define CH 128
#define CIN 256
#define COUT 384
#define KDIM 1152
#define K3 3456      // 3*KDIM for hi/lo split GEMM
#define NB 4

typedef __bf16 bf16x8 __attribute__((ext_vector_type(8)));
typedef float f32x4 __attribute__((ext_vector_type(4)));

__device__ __forceinline__ void gl_lds16(const __bf16* g, __bf16* l) {
    __builtin_amdgcn_global_load_lds(
        (const __attribute__((address_space(1))) unsigned int*)(g),
        (__attribute__((address_space(3))) unsigned int*)(l), 16, 0, 0);
}

// ---------------- copy former+latter passthrough ----------------
__global__ void copy_passthrough(const float* __restrict__ x, float* __restrict__ out) {
    int idx = blockIdx.x * blockDim.x + threadIdx.x; // over NB*CIN*HW
    if (idx >= NB * CIN * HW) return;
    int b = idx / (CIN * HW);
    int rem = idx - b * (CIN * HW);
    out[(size_t)b * COUT * HW + rem] = x[idx];
}

// ---------------- im2col of former -> A2 = [P_hi | P_lo | P_hi] ----------------
__global__ void build_patches_hilo(const float* __restrict__ former, __bf16* __restrict__ A2) {
    int idx = blockIdx.x * blockDim.x + threadIdx.x; // over HW*KDIM
    if (idx >= HW * KDIM) return;
    int i = idx / KDIM, k = idx - i * KDIM;
    int c = k / 9, q = k - c * 9;
    int dy = q / 3, dx = q - dy * 3;
    int y = (i >> 6) + dy - 1, x = (i & 63) + dx - 1;
    float v = 0.f;
    if ((unsigned)y < H && (unsigned)x < W) v = former[c * HW + y * W + x];
    __bf16 hi = (__bf16)v;
    __bf16 lo = (__bf16)(v - (float)hi);
    size_t base = (size_t)i * K3;
    A2[base + k] = hi;
    A2[base + KDIM + k] = lo;
    A2[base + 2 * KDIM + k] = hi;
}

// ---------------- normalized latter windows -> B2 = [WN_hi | WN_hi | WN_lo], den, mm ----------------
__global__ void build_winn_hilo(const float* __restrict__ latter, const float* __restrict__ mask,
                                const int* __restrict__ mask_thred_p,
                                __bf16* __restrict__ B2, float* __restrict__ den, float* __restrict__ mm) {
    int j = blockIdx.x;               // patch index
    int y0 = j >> 6, x0 = j & 63;
    __shared__ float red[256];
    float vals[5];
    float ss = 0.f;
    for (int t = 0; t < 5; ++t) {
        int k = threadIdx.x + t * 256;
        float v = 0.f;
        if (k < KDIM) {
            int c = k / 9, q = k - c * 9;
            int dy = q / 3, dx = q - dy * 3;
            int y = y0 + dy - 1, x = x0 + dx - 1;
            if ((unsigned)y < H && (unsigned)x < W) v = latter[c * HW + y * W + x];
        }
        vals[t] = v;
        ss += v * v;
    }
    red[threadIdx.x] = ss;
    __syncthreads();
    for (int s = 128; s > 0; s >>= 1) {
        if (threadIdx.x < s) red[threadIdx.x] += red[threadIdx.x + s];
        __syncthreads();
    }
    float d = fmaxf(sqrtf(red[0]), 1e-4f);
    float inv = 1.f / d;
    size_t base = (size_t)j * K3;
    for (int t = 0; t < 5; ++t) {
        int k = threadIdx.x + t * 256;
        if (k < KDIM) {
            float v = vals[t] * inv;
            __bf16 hi = (__bf16)v;
            __bf16 lo = (__bf16)(v - (float)hi);
            B2[base + k] = hi;
            B2[base + KDIM + k] = hi;
            B2[base + 2 * KDIM + k] = lo;
        }
    }
    if (threadIdx.x == 0) {
        den[j] = d;
        float s = 0.f;
        for (int q = 0; q < 9; ++q) {
            int dy = q / 3, dx = q - dy * 3;
            int y = y0 + dy - 1, x = x0 + dx - 1;
            if ((unsigned)y < H && (unsigned)x < W) s += mask[y * W + x];
        }
        float mmean = s / 9.f;
        float thr = (float)mask_thred_p[0] / 9.f;
        mm[j] = (mmean <= thr) ? 1.f : 0.f;
    }
}

// ---------------- GEMM1: MFMA bf16 NT, 128x128 tile, BK=64, XOR-swizzled LDS ----------------
__launch_bounds__(256)
__global__ void gemm_bf16_nt(const __bf16* __restrict__ A, const __bf16* __restrict__ B,
                             float* __restrict__ C, int K, int ldc) {
    __shared__ __bf16 As[128 * 64];
    __shared__ __bf16 Bs[128 * 64];
    int tid = threadIdx.x;
    int wave = tid >> 6, lane = tid & 63;
    int quad = lane >> 4, lr = lane & 15;
    int wr = wave >> 1, wc = wave & 1;
    int i0 = blockIdx.y * 128, j0 = blockIdx.x * 128;

    int r0 = tid >> 3;                       // 0..31
    int lk = ((tid & 7) ^ ((tid >> 3) & 7)) * 8;

    f32x4 acc[4][4];
    #pragma unroll
    for (int a = 0; a < 4; ++a)
        #pragma unroll
        for (int b = 0; b < 4; ++b) acc[a][b] = (f32x4){0.f, 0.f, 0.f, 0.f};

    const __bf16* Ab = A + (size_t)i0 * K;
    const __bf16* Bb = B + (size_t)j0 * K;

    int ra[4][2], rb[4][2];
    #pragma unroll
    for (int t = 0; t < 4; ++t) {
        int rowA = wr * 64 + t * 16 + lr;
        int rowB = wc * 64 + t * 16 + lr;
        #pragma unroll
        for (int s = 0; s < 2; ++s) {
            ra[t][s] = rowA * 64 + (((quad + 4 * s) ^ (lr & 7)) * 8);
            rb[t][s] = rowB * 64 + (((quad + 4 * s) ^ (lr & 7)) * 8);
        }
    }

    for (int k0 = 0; k0 < K; k0 += 64) {
        __syncthreads();
        #pragma unroll
        for (int j = 0; j < 4; ++j) {
            int row = r0 + j * 32;
            gl_lds16(Ab + (size_t)row * K + k0 + lk, As + (tid + j * 256) * 8);
            gl_lds16(Bb + (size_t)row * K + k0 + lk, Bs + (tid + j * 256) * 8);
        }
        __syncthreads();
        #pragma unroll
        for (int s = 0; s < 2; ++s) {
            bf16x8 af[4], bfr[4];
            #pragma unroll
            for (int mi = 0; mi < 4; ++mi) af[mi] = *(const bf16x8*)(As + ra[mi][s]);
            #pragma unroll
            for (int ni = 0; ni < 4; ++ni) bfr[ni] = *(const bf16x8*)(Bs + rb[ni][s]);
            #pragma unroll
            for (int mi = 0; mi < 4; ++mi)
                #pragma unroll
                for (int ni = 0; ni < 4; ++ni)
                    acc[mi][ni] = __builtin_amdgcn_mfma_f32_16x16x32_bf16(af[mi], bfr[ni], acc[mi][ni], 0, 0, 0);
        }
    }

    #pragma unroll
    for (int mi = 0; mi < 4; ++mi) {
        #pragma unroll
        for (int r = 0; r < 4; ++r) {
            int row = i0 + wr * 64 + mi * 16 + quad * 4 + r;
            float* Cr = C + (size_t)row * ldc + j0 + wc * 64 + lr;
            #pragma unroll
            for (int ni = 0; ni < 4; ++ni)
                Cr[ni * 16] = acc[mi][ni][r];
        }
    }
}

// ---------------- GEMM2: MFMA bf16 NT, 128(M)x64(N) tile, BK=64 ----------------
__launch_bounds__(256)
__global__ void gemm2_bf16_nt(const __bf16* __restrict__ A, const __bf16* __restrict__ B,
                              float* __restrict__ C, int K, int ldc) {
    __shared__ __bf16 As[128 * 64];
    __shared__ __bf16 Bs[64 * 64];
    int tid = threadIdx.x;
    int wave = tid >> 6, lane = tid & 63;
    int quad = lane >> 4, lr = lane & 15;
    int wr = wave >> 1, wc = wave & 1;
    int i0 = blockIdx.y * 128, j0 = blockIdx.x * 64;

    int r0 = tid >> 3;
    int lk = ((tid & 7) ^ ((tid >> 3) & 7)) * 8;

    f32x4 acc[4][2];
    #pragma unroll
    for (int a = 0; a < 4; ++a)
        #pragma unroll
        for (int b = 0; b < 2; ++b) acc[a][b] = (f32x4){0.f, 0.f, 0.f, 0.f};

    const __bf16* Ab = A + (size_t)i0 * K;
    const __bf16* Bb = B + (size_t)j0 * K;

    int ra[4][2], rb[2][2];
    #pragma unroll
    for (int t = 0; t < 4; ++t) {
        int rowA = wr * 64 + t * 16 + lr;
        #pragma unroll
        for (int s = 0; s < 2; ++s)
            ra[t][s] = rowA * 64 + (((quad + 4 * s) ^ (lr & 7)) * 8);
    }
    #pragma unroll
    for (int t = 0; t < 2; ++t) {
        int rowB = wc * 32 + t * 16 + lr;
        #pragma unroll
        for (int s = 0; s < 2; ++s)
            rb[t][s] = rowB * 64 + (((quad + 4 * s) ^ (lr & 7)) * 8);
    }

    for (int k0 = 0; k0 < K; k0 += 64) {
        __syncthreads();
        #pragma unroll
        for (int j = 0; j < 4; ++j) {
            int row = r0 + j * 32;
            gl_lds16(Ab + (size_t)row * K + k0 + lk, As + (tid + j * 256) * 8);
        }
        #pragma unroll
        for (int j = 0; j < 2; ++j) {
            int row = r0 + j * 32;
            gl_lds16(Bb + (size_t)row * K + k0 + lk, Bs + (tid + j * 256) * 8);
        }
        __syncthreads();
        #pragma unroll
        for (int s = 0; s < 2; ++s) {
            bf16x8 af[4], bfr[2];
            #pragma unroll
            for (int mi = 0; mi < 4; ++mi) af[mi] = *(const bf16x8*)(As + ra[mi][s]);
            #pragma unroll
            for (int ni = 0; ni < 2; ++ni) bfr[ni] = *(const bf16x8*)(Bs + rb[ni][s]);
            #pragma unroll
            for (int mi = 0; mi < 4; ++mi)
                #pragma unroll
                for (int ni = 0; ni < 2; ++ni)
                    acc[mi][ni] = __builtin_amdgcn_mfma_f32_16x16x32_bf16(af[mi], bfr[ni], acc[mi][ni], 0, 0, 0);
        }
    }

    #pragma unroll
    for (int mi = 0; mi < 4; ++mi) {
        #pragma unroll
        for (int r = 0; r < 4; ++r) {
            int row = i0 + wr * 64 + mi * 16 + quad * 4 + r;
            float* Cr = C + (size_t)row * ldc + j0 + wc * 32 + lr;
            #pragma unroll
            for (int ni = 0; ni < 2; ++ni)
                Cr[ni * 16] = acc[mi][ni][r];
        }
    }
}

// ---------------- pass A: 2 output rows/block, XCD-swizzled, XOR-pitch64 LDS ----------------
// E1[rm(p), h] = sum_{d1} S[p+d1, rm(h)+d1] (bounds-checked). Block stages S rows
// p0-1..p0+2 transposed; XOR swizzle keeps both store and read conflict-free.
__launch_bounds__(256)
__global__ void diag_perm2(const float* __restrict__ S, float* __restrict__ E1) {
    int bid = blockIdx.x;                        // 0..2047
    int pair = (bid & 7) * 256 + (bid >> 3);     // XCD-contiguous p ranges
    int p0 = pair * 2;                           // p0 even, p0&63 <= 62
    __shared__ float lds[4][64 * 64];            // 64 KB exactly
    for (int rr = 0; rr < 4; ++rr) {
        int pr = p0 + rr - 1;
        bool v = (unsigned)pr < HW;
        const float* Sr = S + (size_t)pr * HW;
        for (int idx = threadIdx.x; idx < HW; idx += 256) {
            float val = v ? Sr[idx] : 0.f;
            lds[rr][((idx & 63) << 6) | ((idx >> 6) ^ (idx & 63))] = val;
        }
    }
    __syncthreads();
    #pragma unroll
    for (int po = 0; po < 2; ++po) {
        int p = p0 + po;
        int g = ((p & 63) << 6) | (p >> 6);      // rm(p)
        for (int h = threadIdx.x; h < HW; h += 256) {
            int q = ((h & 63) << 6) | (h >> 6);  // rm(h)
            float s = 0.f;
            #pragma unroll
            for (int d1 = -1; d1 <= 1; ++d1) {
                int pp = p + d1, qq = q + d1;
                if ((unsigned)pp < HW && (unsigned)qq < HW)
                    s += lds[po + d1 + 1][((qq & 63) << 6) | ((qq >> 6) ^ (qq & 63))];
            }
            E1[(size_t)g * HW + h] = s;
        }
    }
}

// ---------------- pass B: D2 = diagbox3(E1); softmax over h; *mm*den; bf16 out ----------------
__launch_bounds__(256)
__global__ void diag_softmax(const float* __restrict__ E1, const float* __restrict__ mm,
                             const float* __restrict__ den, __bf16* __restrict__ YB) {
    int g = (blockIdx.x & 7) * 512 + (blockIdx.x >> 3);   // XCD-contiguous g ranges
    __shared__ float red[256];
    float lv[16], sv[16];
    float lmax = -1e30f;
    #pragma unroll
    for (int t = 0; t < 16; ++t) {
        int h = threadIdx.x + t * 256;
        float s = 0.f;
        #pragma unroll
        for (int d2 = -1; d2 <= 1; ++d2) {
            int gg = g + d2, hh = h + d2;
            if ((unsigned)gg < HW && (unsigned)hh < HW)
                s += E1[(size_t)gg * HW + hh];
        }
        int j = ((h & 63) << 6) | (h >> 6);  // rm(h)
        float m = mm[j];
        float l = 10.f * s * m;
        lv[t] = l;
        sv[t] = m * den[j];
        lmax = fmaxf(lmax, l);
    }
    red[threadIdx.x] = lmax;
    __syncthreads();
    for (int s = 128; s > 0; s >>= 1) {
        if (threadIdx.x < s) red[threadIdx.x] = fmaxf(red[threadIdx.x], red[threadIdx.x + s]);
        __syncthreads();
    }
    float M = red[0];
    __syncthreads();
    float ev[16];
    float ssum = 0.f;
    #pragma unroll
    for (int t = 0; t < 16; ++t) {
        ev[t] = expf(lv[t] - M);
        ssum += ev[t];
    }
    red[threadIdx.x] = ssum;
    __syncthreads();
    for (int s = 128; s > 0; s >>= 1) {
        if (threadIdx.x < s) red[threadIdx.x] += red[threadIdx.x + s];
        __syncthreads();
    }
    float inv = 1.f / red[0];
    #pragma unroll
    for (int t = 0; t < 16; ++t) {
        int h = threadIdx.x + t * 256;
        YB[(size_t)g * HW + h] = (__bf16)(ev[t] * inv * sv[t]);
    }
}

// ---------------- WNT[n, h] = WN_hi[rm(h)][n]  (bf16, K-contiguous for GEMM2) ----------------
__launch_bounds__(256)
__global__ void wnt_transpose(const __bf16* __restrict__ B2, __bf16* __restrict__ WNT) {
    int bx = blockIdx.x;
    int by = blockIdx.y;
    int n0 = by * 64;
    __shared__ unsigned short tile[64][72];
    for (int c = threadIdx.x; c < 512; c += 256) {
        int l = c >> 3, seg = c & 7;
        int j = l * 64 + bx;
        uint4 v = *(const uint4*)(B2 + (size_t)j * K3 + n0 + seg * 8);
        *(uint4*)&tile[l][seg * 8] = v;
    }
    __syncthreads();
    for (int c = threadIdx.x; c < 512; c += 256) {
        int r = c >> 3, seg = c & 7;
        unsigned short tmp[8];
        #pragma unroll
        for (int u = 0; u < 8; ++u) tmp[u] = tile[seg * 8 + u][r];
        *(uint4*)(WNT + (size_t)(n0 + r) * HW + bx * 64 + seg * 8) = *(uint4*)tmp;
    }
}

// ---------------- fold C2T (KDIM x HW, cols g = x*64+y) into shift output ----------------
__launch_bounds__(256)
__global__ void fold_out_t(const float* __restrict__ C2T, float* __restrict__ outb) {
    int c = blockIdx.x;
    __shared__ float lds[64 * 65];
    const float* base = C2T + (size_t)c * 9 * HW;
    #pragma unroll 4
    for (int t = 0; t < 16; ++t) {
        int pos = threadIdx.x + t * 256;
        int x = pos >> 6, y = pos & 63;
        float s = 0.f;
        #pragma unroll
        for (int dy = 0; dy < 3; ++dy) {
            int yy = y + 1 - dy;
            if ((unsigned)yy >= 64) continue;
            #pragma unroll
            for (int dx = 0; dx < 3; ++dx) {
                int xx = x + 1 - dx;
                if ((unsigned)xx >= 64) continue;
                s += base[(size_t)(dy * 3 + dx) * HW + xx * 64 + yy];
            }
        }
        lds[y * 65 + x] = s * (1.f / 9.f);
    }
    __syncthreads();
    #pragma unroll 4
    for (int t = 0; t < 16; ++t) {
        int pix = threadIdx.x + t * 256;
        outb[(size_t)(CIN + c) * HW + pix] = lds[(pix >> 6) * 65 + (pix & 63)];
    }
}

extern "C" void kernel_launch(void* const* d_in, const int* in_sizes, int n_in,
                              void* d_out, int out_size, void* d_ws, size_t ws_size,
                              hipStream_t stream) {
    const float* x = (const float*)d_in[0];
    const float* mask = (const float*)d_in[1];
    const int* mask_thred = (const int*)d_in[3];
    float* out = (float*)d_out;

    char* ws = (char*)d_ws;
    __bf16* A2 = (__bf16*)(ws);
    __bf16* B2 = (__bf16*)(ws + 28311552);
    float*  S  = (float*)(ws + 56623104);
    float*  E1 = (float*)(ws + 123731968);
    float* den = (float*)(ws + 190840832);
    float* mmb = (float*)(ws + 190857216);
    __bf16* YB  = (__bf16*)S;
    __bf16* WNT = (__bf16*)E1;
    float*  C2T = (float*)(ws + 123731968 + 9437184);

    copy_passthrough<<<(NB * CIN * HW + 255) / 256, 256, 0, stream>>>(x, out);

    for (int b = 0; b < NB; ++b) {
        const float* xb = x + (size_t)b * CIN * HW;
        const float* former = xb;
        const float* latter = xb + (size_t)CH * HW;
        const float* maskb = mask + (size_t)b * HW;
        float* outb = out + (size_t)b * COUT * HW;

        build_patches_hilo<<<(HW * KDIM + 255) / 256, 256, 0, stream>>>(former, A2);
        build_winn_hilo<<<HW, 256, 0, stream>>>(latter, maskb, mask_thred, B2, den, mmb);
        gemm_bf16_nt<<<dim3(32, 32), 256, 0, stream>>>(A2, B2, S, K3, HW);
        diag_perm2<<<HW / 2, 256, 0, stream>>>(S, E1);
        diag_softmax<<<HW, 256, 0, stream>>>(E1, mmb, den, YB);
        wnt_transpose<<<dim3(64, KDIM / 64), 256, 0, stream>>>(B2, WNT);
        gemm2_bf16_nt<<<dim3(64, KDIM / 128), 256, 0, stream>>>(WNT, YB, C2T, HW, HW);
        fold_out_t<<<CH, 256, 0, stream>>>(C2T, outb);
    }
}

// Round 6
// 1495.663 us; speedup vs baseline: 1.4059x; 1.2126x over previous
//
#include <hip/hip_runtime.h>
#include <math.h>

#define H 64
#define W 64
#define HW 4096
#define CH 128
#define CIN 256
#define COUT 384
#define KDIM 1152
#define NB 4

typedef _Float16 f16x8 __attribute__((ext_vector_type(8)));
typedef float f32x4 __attribute__((ext_vector_type(4)));

__device__ __forceinline__ void gl_lds16(const _Float16* g, _Float16* l) {
    __builtin_amdgcn_global_load_lds(
        (const __attribute__((address_space(1))) unsigned int*)(g),
        (__attribute__((address_space(3))) unsigned int*)(l), 16, 0, 0);
}

// ---------------- copy former+latter passthrough ----------------
__global__ void copy_passthrough(const float* __restrict__ x, float* __restrict__ out) {
    int idx = blockIdx.x * blockDim.x + threadIdx.x; // over NB*CIN*HW
    if (idx >= NB * CIN * HW) return;
    int b = idx / (CIN * HW);
    int rem = idx - b * (CIN * HW);
    out[(size_t)b * COUT * HW + rem] = x[idx];
}

// ---------------- im2col of former -> P (HW x KDIM, f16) ----------------
__global__ void build_patches_f16(const float* __restrict__ former, _Float16* __restrict__ P) {
    int idx = blockIdx.x * blockDim.x + threadIdx.x; // over HW*KDIM
    if (idx >= HW * KDIM) return;
    int i = idx / KDIM, k = idx - i * KDIM;
    int c = k / 9, q = k - c * 9;
    int dy = q / 3, dx = q - dy * 3;
    int y = (i >> 6) + dy - 1, x = (i & 63) + dx - 1;
    float v = 0.f;
    if ((unsigned)y < H && (unsigned)x < W) v = former[c * HW + y * W + x];
    P[(size_t)i * KDIM + k] = (_Float16)v;
}

// ---------------- normalized latter windows -> WN (f16), den, mm ----------------
__global__ void build_winn_f16(const float* __restrict__ latter, const float* __restrict__ mask,
                               const int* __restrict__ mask_thred_p,
                               _Float16* __restrict__ WN, float* __restrict__ den, float* __restrict__ mm) {
    int j = blockIdx.x;               // patch index
    int y0 = j >> 6, x0 = j & 63;
    __shared__ float red[256];
    float vals[5];
    float ss = 0.f;
    for (int t = 0; t < 5; ++t) {
        int k = threadIdx.x + t * 256;
        float v = 0.f;
        if (k < KDIM) {
            int c = k / 9, q = k - c * 9;
            int dy = q / 3, dx = q - dy * 3;
            int y = y0 + dy - 1, x = x0 + dx - 1;
            if ((unsigned)y < H && (unsigned)x < W) v = latter[c * HW + y * W + x];
        }
        vals[t] = v;
        ss += v * v;
    }
    red[threadIdx.x] = ss;
    __syncthreads();
    for (int s = 128; s > 0; s >>= 1) {
        if (threadIdx.x < s) red[threadIdx.x] += red[threadIdx.x + s];
        __syncthreads();
    }
    float d = fmaxf(sqrtf(red[0]), 1e-4f);
    float inv = 1.f / d;
    for (int t = 0; t < 5; ++t) {
        int k = threadIdx.x + t * 256;
        if (k < KDIM) WN[(size_t)j * KDIM + k] = (_Float16)(vals[t] * inv);
    }
    if (threadIdx.x == 0) {
        den[j] = d;
        float s = 0.f;
        for (int q = 0; q < 9; ++q) {
            int dy = q / 3, dx = q - dy * 3;
            int y = y0 + dy - 1, x = x0 + dx - 1;
            if ((unsigned)y < H && (unsigned)x < W) s += mask[y * W + x];
        }
        float mmean = s / 9.f;
        float thr = (float)mask_thred_p[0] / 9.f;
        mm[j] = (mmean <= thr) ? 1.f : 0.f;
    }
}

// ---------------- GEMM1: MFMA f16 NT, 128x128 tile, BK=64, XOR-swizzled LDS ----------------
__launch_bounds__(256)
__global__ void gemm_f16_nt(const _Float16* __restrict__ A, const _Float16* __restrict__ B,
                            float* __restrict__ C, int K, int ldc) {
    __shared__ _Float16 As[128 * 64];
    __shared__ _Float16 Bs[128 * 64];
    int tid = threadIdx.x;
    int wave = tid >> 6, lane = tid & 63;
    int quad = lane >> 4, lr = lane & 15;
    int wr = wave >> 1, wc = wave & 1;
    int i0 = blockIdx.y * 128, j0 = blockIdx.x * 128;

    int r0 = tid >> 3;                       // 0..31
    int lk = ((tid & 7) ^ ((tid >> 3) & 7)) * 8;

    f32x4 acc[4][4];
    #pragma unroll
    for (int a = 0; a < 4; ++a)
        #pragma unroll
        for (int b = 0; b < 4; ++b) acc[a][b] = (f32x4){0.f, 0.f, 0.f, 0.f};

    const _Float16* Ab = A + (size_t)i0 * K;
    const _Float16* Bb = B + (size_t)j0 * K;

    int ra[4][2], rb[4][2];
    #pragma unroll
    for (int t = 0; t < 4; ++t) {
        int rowA = wr * 64 + t * 16 + lr;
        int rowB = wc * 64 + t * 16 + lr;
        #pragma unroll
        for (int s = 0; s < 2; ++s) {
            ra[t][s] = rowA * 64 + (((quad + 4 * s) ^ (lr & 7)) * 8);
            rb[t][s] = rowB * 64 + (((quad + 4 * s) ^ (lr & 7)) * 8);
        }
    }

    for (int k0 = 0; k0 < K; k0 += 64) {
        __syncthreads();
        #pragma unroll
        for (int j = 0; j < 4; ++j) {
            int row = r0 + j * 32;
            gl_lds16(Ab + (size_t)row * K + k0 + lk, As + (tid + j * 256) * 8);
            gl_lds16(Bb + (size_t)row * K + k0 + lk, Bs + (tid + j * 256) * 8);
        }
        __syncthreads();
        #pragma unroll
        for (int s = 0; s < 2; ++s) {
            f16x8 af[4], bfr[4];
            #pragma unroll
            for (int mi = 0; mi < 4; ++mi) af[mi] = *(const f16x8*)(As + ra[mi][s]);
            #pragma unroll
            for (int ni = 0; ni < 4; ++ni) bfr[ni] = *(const f16x8*)(Bs + rb[ni][s]);
            #pragma unroll
            for (int mi = 0; mi < 4; ++mi)
                #pragma unroll
                for (int ni = 0; ni < 4; ++ni)
                    acc[mi][ni] = __builtin_amdgcn_mfma_f32_16x16x32_f16(af[mi], bfr[ni], acc[mi][ni], 0, 0, 0);
        }
    }

    #pragma unroll
    for (int mi = 0; mi < 4; ++mi) {
        #pragma unroll
        for (int r = 0; r < 4; ++r) {
            int row = i0 + wr * 64 + mi * 16 + quad * 4 + r;
            float* Cr = C + (size_t)row * ldc + j0 + wc * 64 + lr;
            #pragma unroll
            for (int ni = 0; ni < 4; ++ni)
                Cr[ni * 16] = acc[mi][ni][r];
        }
    }
}

// ---------------- GEMM2: MFMA f16 NT, 128(M)x64(N) tile, BK=64 ----------------
__launch_bounds__(256)
__global__ void gemm2_f16_nt(const _Float16* __restrict__ A, const _Float16* __restrict__ B,
                             float* __restrict__ C, int K, int ldc) {
    __shared__ _Float16 As[128 * 64];
    __shared__ _Float16 Bs[64 * 64];
    int tid = threadIdx.x;
    int wave = tid >> 6, lane = tid & 63;
    int quad = lane >> 4, lr = lane & 15;
    int wr = wave >> 1, wc = wave & 1;
    int i0 = blockIdx.y * 128, j0 = blockIdx.x * 64;

    int r0 = tid >> 3;
    int lk = ((tid & 7) ^ ((tid >> 3) & 7)) * 8;

    f32x4 acc[4][2];
    #pragma unroll
    for (int a = 0; a < 4; ++a)
        #pragma unroll
        for (int b = 0; b < 2; ++b) acc[a][b] = (f32x4){0.f, 0.f, 0.f, 0.f};

    const _Float16* Ab = A + (size_t)i0 * K;
    const _Float16* Bb = B + (size_t)j0 * K;

    int ra[4][2], rb[2][2];
    #pragma unroll
    for (int t = 0; t < 4; ++t) {
        int rowA = wr * 64 + t * 16 + lr;
        #pragma unroll
        for (int s = 0; s < 2; ++s)
            ra[t][s] = rowA * 64 + (((quad + 4 * s) ^ (lr & 7)) * 8);
    }
    #pragma unroll
    for (int t = 0; t < 2; ++t) {
        int rowB = wc * 32 + t * 16 + lr;
        #pragma unroll
        for (int s = 0; s < 2; ++s)
            rb[t][s] = rowB * 64 + (((quad + 4 * s) ^ (lr & 7)) * 8);
    }

    for (int k0 = 0; k0 < K; k0 += 64) {
        __syncthreads();
        #pragma unroll
        for (int j = 0; j < 4; ++j) {
            int row = r0 + j * 32;
            gl_lds16(Ab + (size_t)row * K + k0 + lk, As + (tid + j * 256) * 8);
        }
        #pragma unroll
        for (int j = 0; j < 2; ++j) {
            int row = r0 + j * 32;
            gl_lds16(Bb + (size_t)row * K + k0 + lk, Bs + (tid + j * 256) * 8);
        }
        __syncthreads();
        #pragma unroll
        for (int s = 0; s < 2; ++s) {
            f16x8 af[4], bfr[2];
            #pragma unroll
            for (int mi = 0; mi < 4; ++mi) af[mi] = *(const f16x8*)(As + ra[mi][s]);
            #pragma unroll
            for (int ni = 0; ni < 2; ++ni) bfr[ni] = *(const f16x8*)(Bs + rb[ni][s]);
            #pragma unroll
            for (int mi = 0; mi < 4; ++mi)
                #pragma unroll
                for (int ni = 0; ni < 2; ++ni)
                    acc[mi][ni] = __builtin_amdgcn_mfma_f32_16x16x32_f16(af[mi], bfr[ni], acc[mi][ni], 0, 0, 0);
        }
    }

    #pragma unroll
    for (int mi = 0; mi < 4; ++mi) {
        #pragma unroll
        for (int r = 0; r < 4; ++r) {
            int row = i0 + wr * 64 + mi * 16 + quad * 4 + r;
            float* Cr = C + (size_t)row * ldc + j0 + wc * 32 + lr;
            #pragma unroll
            for (int ni = 0; ni < 2; ++ni)
                Cr[ni * 16] = acc[mi][ni][r];
        }
    }
}

// ---------------- pass A: 2 output rows/block, XCD-swizzled, XOR-pitch64 LDS ----------------
__launch_bounds__(256)
__global__ void diag_perm2(const float* __restrict__ S, float* __restrict__ E1) {
    int bid = blockIdx.x;                        // 0..2047
    int pair = (bid & 7) * 256 + (bid >> 3);     // XCD-contiguous p ranges
    int p0 = pair * 2;
    __shared__ float lds[4][64 * 64];            // 64 KB exactly
    for (int rr = 0; rr < 4; ++rr) {
        int pr = p0 + rr - 1;
        bool v = (unsigned)pr < HW;
        const float* Sr = S + (size_t)pr * HW;
        for (int idx = threadIdx.x; idx < HW; idx += 256) {
            float val = v ? Sr[idx] : 0.f;
            lds[rr][((idx & 63) << 6) | ((idx >> 6) ^ (idx & 63))] = val;
        }
    }
    __syncthreads();
    #pragma unroll
    for (int po = 0; po < 2; ++po) {
        int p = p0 + po;
        int g = ((p & 63) << 6) | (p >> 6);      // rm(p)
        for (int h = threadIdx.x; h < HW; h += 256) {
            int q = ((h & 63) << 6) | (h >> 6);  // rm(h)
            float s = 0.f;
            #pragma unroll
            for (int d1 = -1; d1 <= 1; ++d1) {
                int pp = p + d1, qq = q + d1;
                if ((unsigned)pp < HW && (unsigned)qq < HW)
                    s += lds[po + d1 + 1][((qq & 63) << 6) | ((qq >> 6) ^ (qq & 63))];
            }
            E1[(size_t)g * HW + h] = s;
        }
    }
}

// ---------------- pass B: D2 = diagbox3(E1); softmax over h; *mm*den; f16 out ----------------
__launch_bounds__(256)
__global__ void diag_softmax(const float* __restrict__ E1, const float* __restrict__ mm,
                             const float* __restrict__ den, _Float16* __restrict__ YB) {
    int g = (blockIdx.x & 7) * 512 + (blockIdx.x >> 3);   // XCD-contiguous g ranges
    __shared__ float red[256];
    float lv[16], sv[16];
    float lmax = -1e30f;
    #pragma unroll
    for (int t = 0; t < 16; ++t) {
        int h = threadIdx.x + t * 256;
        float s = 0.f;
        #pragma unroll
        for (int d2 = -1; d2 <= 1; ++d2) {
            int gg = g + d2, hh = h + d2;
            if ((unsigned)gg < HW && (unsigned)hh < HW)
                s += E1[(size_t)gg * HW + hh];
        }
        int j = ((h & 63) << 6) | (h >> 6);  // rm(h)
        float m = mm[j];
        float l = 10.f * s * m;
        lv[t] = l;
        sv[t] = m * den[j];
        lmax = fmaxf(lmax, l);
    }
    red[threadIdx.x] = lmax;
    __syncthreads();
    for (int s = 128; s > 0; s >>= 1) {
        if (threadIdx.x < s) red[threadIdx.x] = fmaxf(red[threadIdx.x], red[threadIdx.x + s]);
        __syncthreads();
    }
    float M = red[0];
    __syncthreads();
    float ev[16];
    float ssum = 0.f;
    #pragma unroll
    for (int t = 0; t < 16; ++t) {
        ev[t] = expf(lv[t] - M);
        ssum += ev[t];
    }
    red[threadIdx.x] = ssum;
    __syncthreads();
    for (int s = 128; s > 0; s >>= 1) {
        if (threadIdx.x < s) red[threadIdx.x] += red[threadIdx.x + s];
        __syncthreads();
    }
    float inv = 1.f / red[0];
    #pragma unroll
    for (int t = 0; t < 16; ++t) {
        int h = threadIdx.x + t * 256;
        YB[(size_t)g * HW + h] = (_Float16)(ev[t] * inv * sv[t]);
    }
}

// ---------------- WNT[n, h] = WN[rm(h)][n]  (f16, K-contiguous for GEMM2) ----------------
__launch_bounds__(256)
__global__ void wnt_transpose(const _Float16* __restrict__ WN, _Float16* __restrict__ WNT) {
    int bx = blockIdx.x;  // h-tile: h = bx*64 + l -> j = l*64 + bx
    int by = blockIdx.y;  // n-tile
    int n0 = by * 64;
    __shared__ unsigned short tile[64][72];
    for (int c = threadIdx.x; c < 512; c += 256) {
        int l = c >> 3, seg = c & 7;
        int j = l * 64 + bx;
        uint4 v = *(const uint4*)(WN + (size_t)j * KDIM + n0 + seg * 8);
        *(uint4*)&tile[l][seg * 8] = v;
    }
    __syncthreads();
    for (int c = threadIdx.x; c < 512; c += 256) {
        int r = c >> 3, seg = c & 7;
        unsigned short tmp[8];
        #pragma unroll
        for (int u = 0; u < 8; ++u) tmp[u] = tile[seg * 8 + u][r];
        *(uint4*)(WNT + (size_t)(n0 + r) * HW + bx * 64 + seg * 8) = *(uint4*)tmp;
    }
}

// ---------------- fold C2T (KDIM x HW, cols g = x*64+y) into shift output ----------------
__launch_bounds__(256)
__global__ void fold_out_t(const float* __restrict__ C2T, float* __restrict__ outb) {
    int c = blockIdx.x;
    __shared__ float lds[64 * 65];
    const float* base = C2T + (size_t)c * 9 * HW;
    #pragma unroll 4
    for (int t = 0; t < 16; ++t) {
        int pos = threadIdx.x + t * 256;
        int x = pos >> 6, y = pos & 63;
        float s = 0.f;
        #pragma unroll
        for (int dy = 0; dy < 3; ++dy) {
            int yy = y + 1 - dy;
            if ((unsigned)yy >= 64) continue;
            #pragma unroll
            for (int dx = 0; dx < 3; ++dx) {
                int xx = x + 1 - dx;
                if ((unsigned)xx >= 64) continue;
                s += base[(size_t)(dy * 3 + dx) * HW + xx * 64 + yy];
            }
        }
        lds[y * 65 + x] = s * (1.f / 9.f);
    }
    __syncthreads();
    #pragma unroll 4
    for (int t = 0; t < 16; ++t) {
        int pix = threadIdx.x + t * 256;
        outb[(size_t)(CIN + c) * HW + pix] = lds[(pix >> 6) * 65 + (pix & 63)];
    }
}

extern "C" void kernel_launch(void* const* d_in, const int* in_sizes, int n_in,
                              void* d_out, int out_size, void* d_ws, size_t ws_size,
                              hipStream_t stream) {
    const float* x = (const float*)d_in[0];
    const float* mask = (const float*)d_in[1];
    const int* mask_thred = (const int*)d_in[3];
    float* out = (float*)d_out;

    char* ws = (char*)d_ws;
    _Float16* P  = (_Float16*)(ws);                       // 9,437,184 B
    _Float16* WN = (_Float16*)(ws + 9437184);             // 9,437,184 B
    float*  S  = (float*)(ws + 18874368);                 // 67,108,864 B
    float*  E1 = (float*)(ws + 85983232);                 // 67,108,864 B
    float* den = (float*)(ws + 153092096);                // 16,384 B
    float* mmb = (float*)(ws + 153108480);                // 16,384 B
    // aliases (lifetimes disjoint): YB over S; WNT + C2T over E1
    _Float16* YB  = (_Float16*)S;                         // 32 MB region
    _Float16* WNT = (_Float16*)E1;                        // 9.4 MB
    float*  C2T = (float*)(ws + 85983232 + 9437184);      // 18.9 MB

    copy_passthrough<<<(NB * CIN * HW + 255) / 256, 256, 0, stream>>>(x, out);

    for (int b = 0; b < NB; ++b) {
        const float* xb = x + (size_t)b * CIN * HW;
        const float* former = xb;
        const float* latter = xb + (size_t)CH * HW;
        const float* maskb = mask + (size_t)b * HW;
        float* outb = out + (size_t)b * COUT * HW;

        build_patches_f16<<<(HW * KDIM + 255) / 256, 256, 0, stream>>>(former, P);
        build_winn_f16<<<HW, 256, 0, stream>>>(latter, maskb, mask_thred, WN, den, mmb);
        gemm_f16_nt<<<dim3(32, 32), 256, 0, stream>>>(P, WN, S, KDIM, HW);
        diag_perm2<<<HW / 2, 256, 0, stream>>>(S, E1);
        diag_softmax<<<HW, 256, 0, stream>>>(E1, mmb, den, YB);
        wnt_transpose<<<dim3(64, KDIM / 64), 256, 0, stream>>>(WN, WNT);
        // C2T[n][g] = sum_h WNT[n][h] * YB[g][h]  (M=1152, N=4096, K=4096)
        gemm2_f16_nt<<<dim3(64, KDIM / 128), 256, 0, stream>>>(WNT, YB, C2T, HW, HW);
        fold_out_t<<<CH, 256, 0, stream>>>(C2T, outb);
    }
}

// Round 7
// 1118.074 us; speedup vs baseline: 1.8807x; 1.3377x over previous
//
#include <hip/hip_runtime.h>
#include <math.h>

#define H 64
#define W 64
#define HW 4096
#define CH 128
#define CIN 256
#define COUT 384
#define KDIM 1152
#define NB 4

typedef _Float16 f16x8 __attribute__((ext_vector_type(8)));
typedef float f32x4 __attribute__((ext_vector_type(4)));

__device__ __forceinline__ void gl_lds16(const _Float16* g, _Float16* l) {
    __builtin_amdgcn_global_load_lds(
        (const __attribute__((address_space(1))) unsigned int*)(g),
        (__attribute__((address_space(3))) unsigned int*)(l), 16, 0, 0);
}

// ---------------- copy former+latter passthrough ----------------
__global__ void copy_passthrough(const float* __restrict__ x, float* __restrict__ out) {
    int idx = blockIdx.x * blockDim.x + threadIdx.x; // over NB*CIN*HW
    if (idx >= NB * CIN * HW) return;
    int b = idx / (CIN * HW);
    int rem = idx - b * (CIN * HW);
    out[(size_t)b * COUT * HW + rem] = x[idx];
}

// ---------------- im2col of former -> P (HW x KDIM, f16) ----------------
__global__ void build_patches_f16(const float* __restrict__ former, _Float16* __restrict__ P) {
    int idx = blockIdx.x * blockDim.x + threadIdx.x; // over HW*KDIM
    if (idx >= HW * KDIM) return;
    int i = idx / KDIM, k = idx - i * KDIM;
    int c = k / 9, q = k - c * 9;
    int dy = q / 3, dx = q - dy * 3;
    int y = (i >> 6) + dy - 1, x = (i & 63) + dx - 1;
    float v = 0.f;
    if ((unsigned)y < H && (unsigned)x < W) v = former[c * HW + y * W + x];
    P[(size_t)i * KDIM + k] = (_Float16)v;
}

// ---------------- normalized latter windows -> WN (f16), md = {mm, mm*den} ----------------
__global__ void build_winn_f16(const float* __restrict__ latter, const float* __restrict__ mask,
                               const int* __restrict__ mask_thred_p,
                               _Float16* __restrict__ WN, float2* __restrict__ md) {
    int j = blockIdx.x;               // patch index
    int y0 = j >> 6, x0 = j & 63;
    __shared__ float red[256];
    float vals[5];
    float ss = 0.f;
    for (int t = 0; t < 5; ++t) {
        int k = threadIdx.x + t * 256;
        float v = 0.f;
        if (k < KDIM) {
            int c = k / 9, q = k - c * 9;
            int dy = q / 3, dx = q - dy * 3;
            int y = y0 + dy - 1, x = x0 + dx - 1;
            if ((unsigned)y < H && (unsigned)x < W) v = latter[c * HW + y * W + x];
        }
        vals[t] = v;
        ss += v * v;
    }
    red[threadIdx.x] = ss;
    __syncthreads();
    for (int s = 128; s > 0; s >>= 1) {
        if (threadIdx.x < s) red[threadIdx.x] += red[threadIdx.x + s];
        __syncthreads();
    }
    float d = fmaxf(sqrtf(red[0]), 1e-4f);
    float inv = 1.f / d;
    for (int t = 0; t < 5; ++t) {
        int k = threadIdx.x + t * 256;
        if (k < KDIM) WN[(size_t)j * KDIM + k] = (_Float16)(vals[t] * inv);
    }
    if (threadIdx.x == 0) {
        float s = 0.f;
        for (int q = 0; q < 9; ++q) {
            int dy = q / 3, dx = q - dy * 3;
            int y = y0 + dy - 1, x = x0 + dx - 1;
            if ((unsigned)y < H && (unsigned)x < W) s += mask[y * W + x];
        }
        float mmean = s / 9.f;
        float thr = (float)mask_thred_p[0] / 9.f;
        float m = (mmean <= thr) ? 1.f : 0.f;
        md[j] = make_float2(m, m * d);
    }
}

// ---------------- GEMM1: MFMA f16 NT, 128x128 tile, BK=64, XOR-swizzled LDS ----------------
__launch_bounds__(256)
__global__ void gemm_f16_nt(const _Float16* __restrict__ A, const _Float16* __restrict__ B,
                            float* __restrict__ C, int K, int ldc) {
    __shared__ _Float16 As[128 * 64];
    __shared__ _Float16 Bs[128 * 64];
    int tid = threadIdx.x;
    int wave = tid >> 6, lane = tid & 63;
    int quad = lane >> 4, lr = lane & 15;
    int wr = wave >> 1, wc = wave & 1;
    int i0 = blockIdx.y * 128, j0 = blockIdx.x * 128;

    int r0 = tid >> 3;                       // 0..31
    int lk = ((tid & 7) ^ ((tid >> 3) & 7)) * 8;

    f32x4 acc[4][4];
    #pragma unroll
    for (int a = 0; a < 4; ++a)
        #pragma unroll
        for (int b = 0; b < 4; ++b) acc[a][b] = (f32x4){0.f, 0.f, 0.f, 0.f};

    const _Float16* Ab = A + (size_t)i0 * K;
    const _Float16* Bb = B + (size_t)j0 * K;

    int ra[4][2], rb[4][2];
    #pragma unroll
    for (int t = 0; t < 4; ++t) {
        int rowA = wr * 64 + t * 16 + lr;
        int rowB = wc * 64 + t * 16 + lr;
        #pragma unroll
        for (int s = 0; s < 2; ++s) {
            ra[t][s] = rowA * 64 + (((quad + 4 * s) ^ (lr & 7)) * 8);
            rb[t][s] = rowB * 64 + (((quad + 4 * s) ^ (lr & 7)) * 8);
        }
    }

    for (int k0 = 0; k0 < K; k0 += 64) {
        __syncthreads();
        #pragma unroll
        for (int j = 0; j < 4; ++j) {
            int row = r0 + j * 32;
            gl_lds16(Ab + (size_t)row * K + k0 + lk, As + (tid + j * 256) * 8);
            gl_lds16(Bb + (size_t)row * K + k0 + lk, Bs + (tid + j * 256) * 8);
        }
        __syncthreads();
        #pragma unroll
        for (int s = 0; s < 2; ++s) {
            f16x8 af[4], bfr[4];
            #pragma unroll
            for (int mi = 0; mi < 4; ++mi) af[mi] = *(const f16x8*)(As + ra[mi][s]);
            #pragma unroll
            for (int ni = 0; ni < 4; ++ni) bfr[ni] = *(const f16x8*)(Bs + rb[ni][s]);
            #pragma unroll
            for (int mi = 0; mi < 4; ++mi)
                #pragma unroll
                for (int ni = 0; ni < 4; ++ni)
                    acc[mi][ni] = __builtin_amdgcn_mfma_f32_16x16x32_f16(af[mi], bfr[ni], acc[mi][ni], 0, 0, 0);
        }
    }

    #pragma unroll
    for (int mi = 0; mi < 4; ++mi) {
        #pragma unroll
        for (int r = 0; r < 4; ++r) {
            int row = i0 + wr * 64 + mi * 16 + quad * 4 + r;
            float* Cr = C + (size_t)row * ldc + j0 + wc * 64 + lr;
            #pragma unroll
            for (int ni = 0; ni < 4; ++ni)
                Cr[ni * 16] = acc[mi][ni][r];
        }
    }
}

// ---------------- GEMM2: MFMA f16 NT, 128(M)x64(N) tile, BK=64 ----------------
__launch_bounds__(256)
__global__ void gemm2_f16_nt(const _Float16* __restrict__ A, const _Float16* __restrict__ B,
                             float* __restrict__ C, int K, int ldc) {
    __shared__ _Float16 As[128 * 64];
    __shared__ _Float16 Bs[64 * 64];
    int tid = threadIdx.x;
    int wave = tid >> 6, lane = tid & 63;
    int quad = lane >> 4, lr = lane & 15;
    int wr = wave >> 1, wc = wave & 1;
    int i0 = blockIdx.y * 128, j0 = blockIdx.x * 64;

    int r0 = tid >> 3;
    int lk = ((tid & 7) ^ ((tid >> 3) & 7)) * 8;

    f32x4 acc[4][2];
    #pragma unroll
    for (int a = 0; a < 4; ++a)
        #pragma unroll
        for (int b = 0; b < 2; ++b) acc[a][b] = (f32x4){0.f, 0.f, 0.f, 0.f};

    const _Float16* Ab = A + (size_t)i0 * K;
    const _Float16* Bb = B + (size_t)j0 * K;

    int ra[4][2], rb[2][2];
    #pragma unroll
    for (int t = 0; t < 4; ++t) {
        int rowA = wr * 64 + t * 16 + lr;
        #pragma unroll
        for (int s = 0; s < 2; ++s)
            ra[t][s] = rowA * 64 + (((quad + 4 * s) ^ (lr & 7)) * 8);
    }
    #pragma unroll
    for (int t = 0; t < 2; ++t) {
        int rowB = wc * 32 + t * 16 + lr;
        #pragma unroll
        for (int s = 0; s < 2; ++s)
            rb[t][s] = rowB * 64 + (((quad + 4 * s) ^ (lr & 7)) * 8);
    }

    for (int k0 = 0; k0 < K; k0 += 64) {
        __syncthreads();
        #pragma unroll
        for (int j = 0; j < 4; ++j) {
            int row = r0 + j * 32;
            gl_lds16(Ab + (size_t)row * K + k0 + lk, As + (tid + j * 256) * 8);
        }
        #pragma unroll
        for (int j = 0; j < 2; ++j) {
            int row = r0 + j * 32;
            gl_lds16(Bb + (size_t)row * K + k0 + lk, Bs + (tid + j * 256) * 8);
        }
        __syncthreads();
        #pragma unroll
        for (int s = 0; s < 2; ++s) {
            f16x8 af[4], bfr[2];
            #pragma unroll
            for (int mi = 0; mi < 4; ++mi) af[mi] = *(const f16x8*)(As + ra[mi][s]);
            #pragma unroll
            for (int ni = 0; ni < 2; ++ni) bfr[ni] = *(const f16x8*)(Bs + rb[ni][s]);
            #pragma unroll
            for (int mi = 0; mi < 4; ++mi)
                #pragma unroll
                for (int ni = 0; ni < 2; ++ni)
                    acc[mi][ni] = __builtin_amdgcn_mfma_f32_16x16x32_f16(af[mi], bfr[ni], acc[mi][ni], 0, 0, 0);
        }
    }

    #pragma unroll
    for (int mi = 0; mi < 4; ++mi) {
        #pragma unroll
        for (int r = 0; r < 4; ++r) {
            int row = i0 + wr * 64 + mi * 16 + quad * 4 + r;
            float* Cr = C + (size_t)row * ldc + j0 + wc * 32 + lr;
            #pragma unroll
            for (int ni = 0; ni < 2; ++ni)
                Cr[ni * 16] = acc[mi][ni][r];
        }
    }
}

// ---------------- pass A: 2 output rows/block, 512 thr, XCD-swizzled, XOR LDS ----------------
__launch_bounds__(512)
__global__ void diag_perm2(const float* __restrict__ S, float* __restrict__ E1) {
    int bid = blockIdx.x;                        // 0..2047
    int pair = (bid & 7) * 256 + (bid >> 3);     // XCD-contiguous p ranges
    int p0 = pair * 2;
    int tid = threadIdx.x;
    __shared__ float lds[4][64 * 64];            // 64 KB
    for (int rr = 0; rr < 4; ++rr) {
        int pr = p0 + rr - 1;
        bool v = (unsigned)pr < HW;
        const float4* Sr = (const float4*)(S + (size_t)pr * HW);
        #pragma unroll
        for (int k = 0; k < 2; ++k) {
            int i4 = tid + k * 512;              // 0..1023
            int j = i4 * 4;
            float4 val = v ? Sr[i4] : make_float4(0.f, 0.f, 0.f, 0.f);
            float* vp = (float*)&val;
            #pragma unroll
            for (int u = 0; u < 4; ++u) {
                int jj = j + u;
                lds[rr][((jj & 63) << 6) | ((jj >> 6) ^ (jj & 63))] = vp[u];
            }
        }
    }
    __syncthreads();
    #pragma unroll
    for (int po = 0; po < 2; ++po) {
        int p = p0 + po;
        int g = ((p & 63) << 6) | (p >> 6);      // rm(p)
        float* Eg = E1 + (size_t)g * HW;
        #pragma unroll
        for (int t = 0; t < 2; ++t) {
            int h0 = (tid + t * 512) * 4;
            float4 out;
            float* op = (float*)&out;
            #pragma unroll
            for (int u = 0; u < 4; ++u) {
                int h = h0 + u;
                int q = ((h & 63) << 6) | (h >> 6);  // rm(h)
                float s = 0.f;
                #pragma unroll
                for (int d1 = -1; d1 <= 1; ++d1) {
                    int pp = p + d1, qq = q + d1;
                    if ((unsigned)pp < HW && (unsigned)qq < HW)
                        s += lds[po + d1 + 1][((qq & 63) << 6) | ((qq >> 6) ^ (qq & 63))];
                }
                op[u] = s;
            }
            *(float4*)(Eg + h0) = out;
        }
    }
}

// ---------------- pass B: D2 = diagbox3(E1); softmax over h; *mm*den; f16 out ----------------
__launch_bounds__(512)
__global__ void diag_softmax(const float* __restrict__ E1, const float2* __restrict__ md,
                             _Float16* __restrict__ YB) {
    int g = (blockIdx.x & 7) * 512 + (blockIdx.x >> 3);   // XCD-contiguous g ranges
    int tid = threadIdx.x;
    int h0 = tid * 8;
    __shared__ float red[512];
    float D[8] = {0.f, 0.f, 0.f, 0.f, 0.f, 0.f, 0.f, 0.f};
    #pragma unroll
    for (int d2 = -1; d2 <= 1; ++d2) {
        int gg = g + d2;
        if ((unsigned)gg >= HW) continue;
        const float* Er = E1 + (size_t)gg * HW;
        float w[10];  // covers indices h0-1 .. h0+8
        float4 B0 = *(const float4*)(Er + h0);
        float4 B1 = *(const float4*)(Er + h0 + 4);
        w[0] = (h0 > 0) ? Er[h0 - 1] : 0.f;
        w[1] = B0.x; w[2] = B0.y; w[3] = B0.z; w[4] = B0.w;
        w[5] = B1.x; w[6] = B1.y; w[7] = B1.z; w[8] = B1.w;
        w[9] = (h0 + 8 < HW) ? Er[h0 + 8] : 0.f;
        #pragma unroll
        for (int u = 0; u < 8; ++u) {
            int hh = h0 + u + d2;
            if ((unsigned)hh < HW) D[u] += w[u + d2 + 1];
        }
    }
    float lv[8], sv[8];
    float lmax = -1e30f;
    #pragma unroll
    for (int u = 0; u < 8; ++u) {
        int h = h0 + u;
        int j = ((h & 63) << 6) | (h >> 6);  // rm(h)
        float2 m2 = md[j];
        float l = 10.f * D[u] * m2.x;
        lv[u] = l;
        sv[u] = m2.y;
        lmax = fmaxf(lmax, l);
    }
    red[tid] = lmax;
    __syncthreads();
    for (int s = 256; s > 0; s >>= 1) {
        if (tid < s) red[tid] = fmaxf(red[tid], red[tid + s]);
        __syncthreads();
    }
    float M = red[0];
    __syncthreads();
    float ev[8];
    float ssum = 0.f;
    #pragma unroll
    for (int u = 0; u < 8; ++u) {
        ev[u] = expf(lv[u] - M);
        ssum += ev[u];
    }
    red[tid] = ssum;
    __syncthreads();
    for (int s = 256; s > 0; s >>= 1) {
        if (tid < s) red[tid] += red[tid + s];
        __syncthreads();
    }
    float inv = 1.f / red[0];
    f16x8 outv;
    #pragma unroll
    for (int u = 0; u < 8; ++u)
        outv[u] = (_Float16)(ev[u] * inv * sv[u]);
    *(f16x8*)(YB + (size_t)g * HW + h0) = outv;
}

// ---------------- WNT[n, h] = WN[rm(h)][n]  (f16, K-contiguous for GEMM2) ----------------
__launch_bounds__(256)
__global__ void wnt_transpose(const _Float16* __restrict__ WN, _Float16* __restrict__ WNT) {
    int bx = blockIdx.x;  // h-tile: h = bx*64 + l -> j = l*64 + bx
    int by = blockIdx.y;  // n-tile
    int n0 = by * 64;
    __shared__ unsigned short tile[64][72];
    for (int c = threadIdx.x; c < 512; c += 256) {
        int l = c >> 3, seg = c & 7;
        int j = l * 64 + bx;
        uint4 v = *(const uint4*)(WN + (size_t)j * KDIM + n0 + seg * 8);
        *(uint4*)&tile[l][seg * 8] = v;
    }
    __syncthreads();
    for (int c = threadIdx.x; c < 512; c += 256) {
        int r = c >> 3, seg = c & 7;
        unsigned short tmp[8];
        #pragma unroll
        for (int u = 0; u < 8; ++u) tmp[u] = tile[seg * 8 + u][r];
        *(uint4*)(WNT + (size_t)(n0 + r) * HW + bx * 64 + seg * 8) = *(uint4*)tmp;
    }
}

// ---------------- fold C2T (KDIM x HW, cols g = x*64+y) into shift output ----------------
__launch_bounds__(256)
__global__ void fold_out_t(const float* __restrict__ C2T, float* __restrict__ outb) {
    int c = blockIdx.x;
    __shared__ float lds[64 * 65];
    const float* base = C2T + (size_t)c * 9 * HW;
    #pragma unroll 4
    for (int t = 0; t < 16; ++t) {
        int pos = threadIdx.x + t * 256;
        int x = pos >> 6, y = pos & 63;
        float s = 0.f;
        #pragma unroll
        for (int dy = 0; dy < 3; ++dy) {
            int yy = y + 1 - dy;
            if ((unsigned)yy >= 64) continue;
            #pragma unroll
            for (int dx = 0; dx < 3; ++dx) {
                int xx = x + 1 - dx;
                if ((unsigned)xx >= 64) continue;
                s += base[(size_t)(dy * 3 + dx) * HW + xx * 64 + yy];
            }
        }
        lds[y * 65 + x] = s * (1.f / 9.f);
    }
    __syncthreads();
    #pragma unroll 4
    for (int t = 0; t < 16; ++t) {
        int pix = threadIdx.x + t * 256;
        outb[(size_t)(CIN + c) * HW + pix] = lds[(pix >> 6) * 65 + (pix & 63)];
    }
}

extern "C" void kernel_launch(void* const* d_in, const int* in_sizes, int n_in,
                              void* d_out, int out_size, void* d_ws, size_t ws_size,
                              hipStream_t stream) {
    const float* x = (const float*)d_in[0];
    const float* mask = (const float*)d_in[1];
    const int* mask_thred = (const int*)d_in[3];
    float* out = (float*)d_out;

    char* ws = (char*)d_ws;
    _Float16* P  = (_Float16*)(ws);                       // 9,437,184 B
    _Float16* WN = (_Float16*)(ws + 9437184);             // 9,437,184 B
    float*  S  = (float*)(ws + 18874368);                 // 67,108,864 B
    float*  E1 = (float*)(ws + 85983232);                 // 67,108,864 B
    float2* md = (float2*)(ws + 153092096);               // 32,768 B
    // aliases (lifetimes disjoint): YB over S; WNT + C2T over E1
    _Float16* YB  = (_Float16*)S;                         // 32 MB region
    _Float16* WNT = (_Float16*)E1;                        // 9.4 MB
    float*  C2T = (float*)(ws + 85983232 + 9437184);      // 18.9 MB

    copy_passthrough<<<(NB * CIN * HW + 255) / 256, 256, 0, stream>>>(x, out);

    for (int b = 0; b < NB; ++b) {
        const float* xb = x + (size_t)b * CIN * HW;
        const float* former = xb;
        const float* latter = xb + (size_t)CH * HW;
        const float* maskb = mask + (size_t)b * HW;
        float* outb = out + (size_t)b * COUT * HW;

        build_patches_f16<<<(HW * KDIM + 255) / 256, 256, 0, stream>>>(former, P);
        build_winn_f16<<<HW, 256, 0, stream>>>(latter, maskb, mask_thred, WN, md);
        gemm_f16_nt<<<dim3(32, 32), 256, 0, stream>>>(P, WN, S, KDIM, HW);
        diag_perm2<<<HW / 2, 512, 0, stream>>>(S, E1);
        diag_softmax<<<HW, 512, 0, stream>>>(E1, md, YB);
        wnt_transpose<<<dim3(64, KDIM / 64), 256, 0, stream>>>(WN, WNT);
        // C2T[n][g] = sum_h WNT[n][h] * YB[g][h]  (M=1152, N=4096, K=4096)
        gemm2_f16_nt<<<dim3(64, KDIM / 128), 256, 0, stream>>>(WNT, YB, C2T, HW, HW);
        fold_out_t<<<CH, 256, 0, stream>>>(C2T, outb);
    }
}